// Round 7
// baseline (96.311 us; speedup 1.0000x reference)
//
#include <hip/hip_runtime.h>

#define BB 32
#define OO 64
#define II 64
#define FF 16
#define HH 128
#define WW 128

typedef __attribute__((ext_vector_type(8))) __bf16 bf16x8;
typedef __attribute__((ext_vector_type(4))) float f32x4;

typedef __attribute__((address_space(3))) uint8_t  lds_u8;
typedef __attribute__((address_space(1))) const uint8_t g_u8;

// ---------------- Kernel 1: weight/bias generation ----------------
__global__ __launch_bounds__(64)
void gen_weights(const float* __restrict__ addr,
                 const float* __restrict__ w_bank,
                 const float* __restrict__ b_bank,
                 __bf16* __restrict__ wT,
                 float* __restrict__ bias_out) {
    const int bo  = blockIdx.x;            // b*64 + o
    const int tid = threadIdx.x;           // i = 0..63

    __shared__ float bank_s[FF * 9];
    __shared__ float bbank_s[FF];
    for (int idx = tid; idx < FF * 9; idx += 64) bank_s[idx] = w_bank[idx];
    if (tid < FF) bbank_s[tid] = b_bank[tid];
    __syncthreads();

    const float* arow = addr + ((size_t)bo * (II + 1) + 1 + tid) * FF;
    float a[FF];
    float m = -1e30f;
#pragma unroll
    for (int f = 0; f < FF; ++f) { a[f] = arow[f]; m = fmaxf(m, a[f]); }
    float s = 0.f;
#pragma unroll
    for (int f = 0; f < FF; ++f) { a[f] = __expf(a[f] - m); s += a[f]; }
    const float inv = 1.0f / s;

    const int b = bo >> 6, o = bo & 63;
#pragma unroll
    for (int kl = 0; kl < 9; ++kl) {
        float acc = 0.f;
#pragma unroll
        for (int f = 0; f < FF; ++f) acc += a[f] * bank_s[f * 9 + kl];
        wT[(((size_t)b * 9 + kl) * OO + o) * II + tid] = (__bf16)(acc * inv);
    }

    if (tid == 0) {
        const float* brow = addr + (size_t)bo * (II + 1) * FF;
        float bb[FF];
        float bm = -1e30f;
#pragma unroll
        for (int f = 0; f < FF; ++f) { bb[f] = brow[f]; bm = fmaxf(bm, bb[f]); }
        float bs = 0.f;
#pragma unroll
        for (int f = 0; f < FF; ++f) { bb[f] = __expf(bb[f] - bm); bs += bb[f]; }
        float acc = 0.f;
#pragma unroll
        for (int f = 0; f < FF; ++f) acc += bb[f] * bbank_s[f];
        bias_out[bo] = acc / bs;
    }
}

// ---------------- Kernel 2: fused transpose + implicit-GEMM conv ----------------
// 512 threads (8 waves), 1 block/CU (154.5KB LDS). Grid = 256 blocks (1/CU).
// Block: (b, px-half, 32-row group). 8 phases of {4 rows x 64 px x 64 o}.
// A (72KB) staged via global_load_lds once. x reg-staged from raw fp32:
// two pair-stages per phase, each with 9 k-steps of MFMA as latency cover.
// Ring: 10 slots, slot = padded_row % 10 (live 6 + prefetch 4, disjoint).
#define SLOTB 8448               // 66 px * 128 B
#define NSLOT 10
#define RINGOFF 73728            // A region = [0, 73728)
#define LDSZ (RINGOFF + NSLOT * SLOTB)   // 158208 B

// load global x rows (R0+pr-1, R0+pr) [i.e. padded rows pr, pr+1] into sm0/sm1/smt
#define LOADPAIR(pr_) do {                                                         \
    const int pxg_ = ph * 64 + l - 1;                                              \
    const bool okpx_ = (unsigned)pxg_ < 128u;                                      \
    _Pragma("unroll")                                                              \
    for (int j_ = 0; j_ < 2; ++j_) {                                               \
        const int gr_ = R0 + (pr_) + j_ - 1;                                       \
        const bool ok_ = okpx_ && ((unsigned)gr_ < 128u);                          \
        const float* xs_ = xb + ((size_t)(wv * 8) * HH + gr_) * WW + pxg_;         \
        float* dst_ = j_ ? sm1 : sm0;                                              \
        _Pragma("unroll")                                                          \
        for (int jj_ = 0; jj_ < 8; ++jj_) {                                        \
            float v_ = 0.f;                                                        \
            if (ok_) v_ = xs_[(size_t)jj_ * (HH * WW)];                            \
            dst_[jj_] = v_;                                                        \
        }                                                                          \
    }                                                                              \
    {   /* tail: local px 64,65 for both rows; lanes 0..31 of wave 0 */            \
        const int lr_ = l >> 4;                                                    \
        const int cc_ = (l >> 1) & 7;                                              \
        const int pxl_ = 64 + (l & 1);                                             \
        const int pxg2_ = ph * 64 + pxl_ - 1;                                      \
        const int gr_ = R0 + (pr_) + lr_ - 1;                                      \
        const bool ok_ = (t < 32) && ((unsigned)pxg2_ < 128u)                      \
                         && ((unsigned)gr_ < 128u);                                \
        const float* xs_ = xb + ((size_t)(cc_ * 8) * HH + gr_) * WW + pxg2_;       \
        _Pragma("unroll")                                                          \
        for (int jj_ = 0; jj_ < 8; ++jj_) {                                        \
            float v_ = 0.f;                                                        \
            if (ok_) v_ = xs_[(size_t)jj_ * (HH * WW)];                            \
            smt[jj_] = v_;                                                         \
        }                                                                          \
    }                                                                              \
} while (0)

// convert + swizzled ds_write of the pair into ring slots sA_, sB_
#define WRITEPAIR(sA_, sB_) do {                                                   \
    bf16x8 u_;                                                                     \
    _Pragma("unroll")                                                              \
    for (int jj_ = 0; jj_ < 8; ++jj_) u_[jj_] = (__bf16)sm0[jj_];                  \
    *(bf16x8*)(LDS + RINGOFF + (sA_) * SLOTB + l * 128                             \
               + ((wv ^ (l & 7)) << 4)) = u_;                                      \
    _Pragma("unroll")                                                              \
    for (int jj_ = 0; jj_ < 8; ++jj_) u_[jj_] = (__bf16)sm1[jj_];                  \
    *(bf16x8*)(LDS + RINGOFF + (sB_) * SLOTB + l * 128                             \
               + ((wv ^ (l & 7)) << 4)) = u_;                                      \
    if (t < 32) {                                                                  \
        const int lr_ = l >> 4;                                                    \
        const int cc_ = (l >> 1) & 7;                                              \
        const int pxl_ = 64 + (l & 1);                                             \
        const int sl_ = lr_ ? (sB_) : (sA_);                                       \
        _Pragma("unroll")                                                          \
        for (int jj_ = 0; jj_ < 8; ++jj_) u_[jj_] = (__bf16)smt[jj_];              \
        *(bf16x8*)(LDS + RINGOFF + sl_ * SLOTB + pxl_ * 128                        \
                   + ((cc_ ^ (pxl_ & 7)) << 4)) = u_;                              \
    }                                                                              \
} while (0)

// unrolled k-step range [K0_, K1_): 2 A-reads + 4 B-reads + 8 MFMA each
#define KS_RANGE(K0_, K1_) do {                                                    \
    _Pragma("unroll")                                                              \
    for (int ks = (K0_); ks < (K1_); ++ks) {                                       \
        const int kl = ks >> 1, k0 = ks & 1;                                       \
        const int dr = kl / 3, dc = kl - 3 * dr;                                   \
        const int cc = lk + 4 * k0;                                                \
        bf16x8 af[2], bv[4];                                                       \
        _Pragma("unroll")                                                          \
        for (int mf = 0; mf < 2; ++mf)                                             \
            af[mf] = *(const bf16x8*)(LDS + kl * 8192 + (obase0 + mf * 16) * 128   \
                                      + ((cc ^ (lm & 7)) << 4));                   \
        const int lpx = pxbase + dc;                                               \
        const int swb = lpx * 128 + ((cc ^ (lpx & 7)) << 4);                       \
        _Pragma("unroll")                                                          \
        for (int nf = 0; nf < 4; ++nf)                                             \
            bv[nf] = *(const bf16x8*)(LDS + off_[nf + dr] + swb);                  \
        _Pragma("unroll")                                                          \
        for (int mf = 0; mf < 2; ++mf)                                             \
            _Pragma("unroll")                                                      \
            for (int nf = 0; nf < 4; ++nf)                                         \
                acc[mf][nf] = __builtin_amdgcn_mfma_f32_16x16x32_bf16(             \
                    af[mf], bv[nf], acc[mf][nf], 0, 0, 0);                         \
    }                                                                              \
} while (0)

__global__ __launch_bounds__(512, 2)
void conv_fused(const float* __restrict__ x, const __bf16* __restrict__ wT,
                const float* __restrict__ bias, float* __restrict__ y) {
    __shared__ __align__(16) char LDS[LDSZ];

    // bijective XCD swizzle: blocks of one batch share an XCD
    const int hwid = blockIdx.x;
    const int work = (hwid & 7) * 32 + (hwid >> 3);
    const int b  = work >> 3;
    const int r3 = work & 7;
    const int ph = r3 >> 2;                // px half (64 px)
    const int rg = r3 & 3;                 // 32-row group
    const int R0 = rg * 32;

    const int t  = threadIdx.x;
    const int wv = t >> 6;
    const int l  = t & 63;
    const int lm = l & 15;
    const int lk = l >> 4;
    const int oh = wv >> 2;                // o half (32 o)
    const int g  = wv & 3;                 // px-16 group within 64

    const __bf16* wb = wT + (size_t)b * 9 * OO * II;
    const float*  xb = x + (size_t)b * II * HH * WW;

    // ---- prologue: stage A (4608 chunks, source-swizzled) ----
#pragma unroll
    for (int it = 0; it < 9; ++it) {
        const int cid = it * 512 + t;
        const int kl  = cid >> 9;
        const int rem = cid & 511;
        const int o   = rem >> 3;
        const int c   = rem & 7;
        const __bf16* src = wb + ((kl * 64 + o) << 6) + ((c ^ (o & 7)) << 3);
        __builtin_amdgcn_global_load_lds((g_u8*)src,
            (lds_u8*)(LDS + (size_t)(it * 512 + (t & 448)) * 16), 16, 0, 0);
    }

    float sm0[8], sm1[8], smt[8];

    // stage x padded rows 0..5 into slots 0..5
    LOADPAIR(0); WRITEPAIR(0, 1);
    LOADPAIR(2); WRITEPAIR(2, 3);
    LOADPAIR(4); WRITEPAIR(4, 5);

    // bias preload
    float bbias[2][4];
    {
        const float* bp = bias + b * OO;
#pragma unroll
        for (int mf = 0; mf < 2; ++mf)
#pragma unroll
            for (int r = 0; r < 4; ++r)
                bbias[mf][r] = bp[oh * 32 + mf * 16 + lk * 4 + r];
    }
    f32x4 acc[2][4];
#pragma unroll
    for (int mf = 0; mf < 2; ++mf)
#pragma unroll
        for (int nf = 0; nf < 4; ++nf)
#pragma unroll
            for (int r = 0; r < 4; ++r)
                acc[mf][nf][r] = bbias[mf][r];

    __syncthreads();                       // A + rows 0..5 landed

    const int pxbase = g * 16 + lm;        // lane's local px (0..63)
    const int obase0 = oh * 32 + lm;       // lane's A row for mf=0

    int s0 = 0;                            // slot of padded row 4p
    for (int p = 0; p < 8; ++p) {
        int off_[6];
#pragma unroll
        for (int d = 0; d < 6; ++d) {
            int ss = s0 + d; if (ss >= NSLOT) ss -= NSLOT;
            off_[d] = RINGOFF + ss * SLOTB;
        }
        int wA = s0 + 6; if (wA >= NSLOT) wA -= NSLOT;
        int wB = wA + 1; if (wB >= NSLOT) wB -= NSLOT;
        int wC = wB + 1; if (wC >= NSLOT) wC -= NSLOT;
        int wD = wC + 1; if (wD >= NSLOT) wD -= NSLOT;
        const int pr = 4 * p;
        const bool pf = (p < 7);

        if (pf) LOADPAIR(pr + 6);          // issue pair A loads
        KS_RANGE(0, 9);                    // ~1.5us of MFMA covers the latency
        if (pf) { WRITEPAIR(wA, wB); LOADPAIR(pr + 8); }   // land A, issue B
        KS_RANGE(9, 18);
        if (pf) WRITEPAIR(wC, wD);         // land B

        __syncthreads();                   // ring rotated; next rows visible

        // stores (4 rows) + acc reinit
#pragma unroll
        for (int mf = 0; mf < 2; ++mf)
#pragma unroll
            for (int r = 0; r < 4; ++r) {
                const int o = oh * 32 + mf * 16 + lk * 4 + r;
#pragma unroll
                for (int nf = 0; nf < 4; ++nf) {
                    const int rowg = R0 + pr + nf;
                    y[(((size_t)b * OO + o) * HH + rowg) * WW + ph * 64 + pxbase]
                        = acc[mf][nf][r];
                }
            }
#pragma unroll
        for (int mf = 0; mf < 2; ++mf)
#pragma unroll
            for (int nf = 0; nf < 4; ++nf)
#pragma unroll
                for (int r = 0; r < 4; ++r)
                    acc[mf][nf][r] = bbias[mf][r];

        s0 += 4; if (s0 >= NSLOT) s0 -= NSLOT;
    }
}

extern "C" void kernel_launch(void* const* d_in, const int* in_sizes, int n_in,
                              void* d_out, int out_size, void* d_ws, size_t ws_size,
                              hipStream_t stream) {
    const float* addresses = (const float*)d_in[0];   // (B,O,I+1,F)
    const float* x         = (const float*)d_in[1];   // (B,I,H,W)
    const float* w_bank    = (const float*)d_in[2];   // (F,3,3)
    const float* b_bank    = (const float*)d_in[3];   // (F,)
    float* out = (float*)d_out;                       // (B,O,H,W)

    // ws layout: [bias 8KB][wT 2.25MB]
    float*  bias_ws = (float*)d_ws;
    __bf16* wT      = (__bf16*)((char*)d_ws + 8192);

    gen_weights<<<BB * OO, 64, 0, stream>>>(addresses, w_bank, b_bank, wT, bias_ws);
    conv_fused<<<256, 512, 0, stream>>>(x, wT, bias_ws, out);
}

// Round 8
// 80.144 us; speedup vs baseline: 1.2017x; 1.2017x over previous
//
#include <hip/hip_runtime.h>

#define BB 32
#define OO 64
#define II 64
#define FF 16
#define HH 128
#define WW 128

typedef __attribute__((ext_vector_type(8))) __bf16 bf16x8;
typedef __attribute__((ext_vector_type(4))) float f32x4;

typedef __attribute__((address_space(3))) uint8_t  lds_u8;
typedef __attribute__((address_space(1))) const uint8_t g_u8;

// ---------------- Kernel 1: weight/bias generation ----------------
__global__ __launch_bounds__(64)
void gen_weights(const float* __restrict__ addr,
                 const float* __restrict__ w_bank,
                 const float* __restrict__ b_bank,
                 __bf16* __restrict__ wT,
                 float* __restrict__ bias_out) {
    const int bo  = blockIdx.x;            // b*64 + o
    const int tid = threadIdx.x;           // i = 0..63

    __shared__ float bank_s[FF * 9];
    __shared__ float bbank_s[FF];
    for (int idx = tid; idx < FF * 9; idx += 64) bank_s[idx] = w_bank[idx];
    if (tid < FF) bbank_s[tid] = b_bank[tid];
    __syncthreads();

    const float* arow = addr + ((size_t)bo * (II + 1) + 1 + tid) * FF;
    float a[FF];
    float m = -1e30f;
#pragma unroll
    for (int f = 0; f < FF; ++f) { a[f] = arow[f]; m = fmaxf(m, a[f]); }
    float s = 0.f;
#pragma unroll
    for (int f = 0; f < FF; ++f) { a[f] = __expf(a[f] - m); s += a[f]; }
    const float inv = 1.0f / s;

    const int b = bo >> 6, o = bo & 63;
#pragma unroll
    for (int kl = 0; kl < 9; ++kl) {
        float acc = 0.f;
#pragma unroll
        for (int f = 0; f < FF; ++f) acc += a[f] * bank_s[f * 9 + kl];
        wT[(((size_t)b * 9 + kl) * OO + o) * II + tid] = (__bf16)(acc * inv);
    }

    if (tid == 0) {
        const float* brow = addr + (size_t)bo * (II + 1) * FF;
        float bb[FF];
        float bm = -1e30f;
#pragma unroll
        for (int f = 0; f < FF; ++f) { bb[f] = brow[f]; bm = fmaxf(bm, bb[f]); }
        float bs = 0.f;
#pragma unroll
        for (int f = 0; f < FF; ++f) { bb[f] = __expf(bb[f] - bm); bs += bb[f]; }
        float acc = 0.f;
#pragma unroll
        for (int f = 0; f < FF; ++f) acc += bb[f] * bbank_s[f];
        bias_out[bo] = acc / bs;
    }
}

// ---------------- Kernel 2: fused transpose + implicit-GEMM conv ----------------
// 512 threads (8 waves), 1 block/CU (138KB LDS). Grid = 256 blocks (1/CU).
// Block: (b, px-half, 32-row group). 16 phases of {2 rows x 64 px x 64 o}.
// A (72KB) staged via global_load_lds once, then hoisted to 144 VGPRs/thread
// (one-time 36 ds_reads) -> inner loop reads ONLY B from LDS (halves LDS traffic).
// x reg-staged from raw fp32 (T14 async split) into an 8-slot ring.
#define SLOTB 8448               // 66 px * 128 B
#define RINGOFF 73728            // A region = [0, 73728)
#define LDSZ (RINGOFF + 8 * SLOTB)   // 141312 B

// issue loads for ring pair q (padded local rows 2q, 2q+1) into sm0/sm1/smt
#define LOADPAIR(q_) do {                                                          \
    const int pxg_ = ph * 64 + l - 1;                                              \
    const bool okpx_ = (unsigned)pxg_ < 128u;                                      \
    _Pragma("unroll")                                                              \
    for (int j_ = 0; j_ < 2; ++j_) {                                               \
        const int rr_ = R0 + 2 * (q_) + j_ - 1;                                    \
        const bool ok_ = okpx_ && ((unsigned)rr_ < 128u);                          \
        const float* xs_ = xb + ((size_t)(wv * 8) * HH + rr_) * WW + pxg_;         \
        float* dst_ = j_ ? sm1 : sm0;                                              \
        _Pragma("unroll")                                                          \
        for (int jj_ = 0; jj_ < 8; ++jj_) {                                        \
            float v_ = 0.f;                                                        \
            if (ok_) v_ = xs_[(size_t)jj_ * (HH * WW)];                            \
            dst_[jj_] = v_;                                                        \
        }                                                                          \
    }                                                                              \
    {   /* tail: px 64,65 for all 16 (row,cc) combos, lanes 0..31 of wave 0 */     \
        const int lr_ = l >> 4;                                                    \
        const int cc_ = (l >> 1) & 7;                                              \
        const int pxl_ = 64 + (l & 1);                                             \
        const int pxg2_ = ph * 64 + pxl_ - 1;                                      \
        const int rr_ = R0 + 2 * (q_) + lr_ - 1;                                   \
        const bool ok_ = (t < 32) && ((unsigned)pxg2_ < 128u)                      \
                         && ((unsigned)rr_ < 128u);                                \
        const float* xs_ = xb + ((size_t)(cc_ * 8) * HH + rr_) * WW + pxg2_;       \
        _Pragma("unroll")                                                          \
        for (int jj_ = 0; jj_ < 8; ++jj_) {                                        \
            float v_ = 0.f;                                                        \
            if (ok_) v_ = xs_[(size_t)jj_ * (HH * WW)];                            \
            smt[jj_] = v_;                                                         \
        }                                                                          \
    }                                                                              \
} while (0)

// convert + ds_write pair q (implicit vmcnt wait on sm* uses)
#define WRITEPAIR(q_) do {                                                         \
    bf16x8 u_;                                                                     \
    _Pragma("unroll")                                                              \
    for (int jj_ = 0; jj_ < 8; ++jj_) u_[jj_] = (__bf16)sm0[jj_];                  \
    *(bf16x8*)(LDS + RINGOFF + ((2 * (q_)) & 7) * SLOTB + l * 128                  \
               + ((wv ^ (l & 7)) << 4)) = u_;                                      \
    _Pragma("unroll")                                                              \
    for (int jj_ = 0; jj_ < 8; ++jj_) u_[jj_] = (__bf16)sm1[jj_];                  \
    *(bf16x8*)(LDS + RINGOFF + ((2 * (q_) + 1) & 7) * SLOTB + l * 128              \
               + ((wv ^ (l & 7)) << 4)) = u_;                                      \
    if (t < 32) {                                                                  \
        const int lr_ = l >> 4;                                                    \
        const int cc_ = (l >> 1) & 7;                                              \
        const int pxl_ = 64 + (l & 1);                                             \
        _Pragma("unroll")                                                          \
        for (int jj_ = 0; jj_ < 8; ++jj_) u_[jj_] = (__bf16)smt[jj_];              \
        *(bf16x8*)(LDS + RINGOFF + ((2 * (q_) + lr_) & 7) * SLOTB + pxl_ * 128     \
                   + ((cc_ ^ (pxl_ & 7)) << 4)) = u_;                              \
    }                                                                              \
} while (0)

__global__ __launch_bounds__(512, 2)
void conv_fused(const float* __restrict__ x, const __bf16* __restrict__ wT,
                const float* __restrict__ bias, float* __restrict__ y) {
    __shared__ __align__(16) char LDS[LDSZ];

    // bijective XCD swizzle: blocks of one batch share an XCD
    const int hwid = blockIdx.x;
    const int work = (hwid & 7) * 32 + (hwid >> 3);
    const int b  = work >> 3;
    const int r3 = work & 7;
    const int ph = r3 >> 2;                // px half (64 px)
    const int rg = r3 & 3;                 // 32-row group
    const int R0 = rg * 32;

    const int t  = threadIdx.x;
    const int wv = t >> 6;
    const int l  = t & 63;
    const int lm = l & 15;
    const int lk = l >> 4;
    const int oh = wv >> 2;                // o half (32 o)
    const int g  = wv & 3;                 // px-16 group within 64

    const __bf16* wb = wT + (size_t)b * 9 * OO * II;
    const float*  xb = x + (size_t)b * II * HH * WW;

    // ---- prologue: stage A (4608 chunks, source-swizzled) ----
#pragma unroll
    for (int it = 0; it < 9; ++it) {
        const int cid = it * 512 + t;
        const int kl  = cid >> 9;
        const int rem = cid & 511;
        const int o   = rem >> 3;
        const int c   = rem & 7;
        const __bf16* src = wb + ((kl * 64 + o) << 6) + ((c ^ (o & 7)) << 3);
        __builtin_amdgcn_global_load_lds((g_u8*)src,
            (lds_u8*)(LDS + (size_t)(it * 512 + (t & 448)) * 16), 16, 0, 0);
    }

    float sm0[8], sm1[8], smt[8];

    // stage x ring pairs 0,1 (padded local rows 0..3)
    LOADPAIR(0);
    WRITEPAIR(0);
    LOADPAIR(1);
    WRITEPAIR(1);

    // bias preload
    float bbias[2][4];
    {
        const float* bp = bias + b * OO;
#pragma unroll
        for (int mf = 0; mf < 2; ++mf)
#pragma unroll
            for (int r = 0; r < 4; ++r)
                bbias[mf][r] = bp[oh * 32 + mf * 16 + lk * 4 + r];
    }
    f32x4 acc[2][2];
#pragma unroll
    for (int mf = 0; mf < 2; ++mf)
#pragma unroll
        for (int nf = 0; nf < 2; ++nf)
#pragma unroll
            for (int r = 0; r < 4; ++r)
                acc[mf][nf][r] = bbias[mf][r];

    __syncthreads();                       // A + ring pairs 0,1 landed

    const int pxbase = g * 16 + lm;        // lane's local px (0..63)
    const int obase0 = oh * 32 + lm;       // lane's A row for mf=0

    // ---- one-time hoist: A fragments LDS -> 144 VGPRs ----
    bf16x8 Areg[9][2][2];                  // [kl][k0][mf]
#pragma unroll
    for (int kl = 0; kl < 9; ++kl)
#pragma unroll
        for (int k0 = 0; k0 < 2; ++k0)
#pragma unroll
            for (int mf = 0; mf < 2; ++mf) {
                const int cc = lk + 4 * k0;
                Areg[kl][k0][mf] = *(const bf16x8*)(LDS + kl * 8192
                    + (obase0 + mf * 16) * 128 + ((cc ^ (lm & 7)) << 4));
            }

    int s0 = 0;                            // slot base = (2p) & 7

    for (int p = 0; p < 16; ++p) {
        if (p < 15) LOADPAIR(p + 2);       // issue next pair's global loads

#pragma unroll
        for (int ks = 0; ks < 18; ++ks) {
            const int kl = ks >> 1, k0 = ks & 1;
            const int dr = kl / 3, dc = kl - 3 * dr;
            const int cc = lk + 4 * k0;    // logical 16B chunk of the k-slice
            bf16x8 bv[2];
            const int lpx = pxbase + dc;
#pragma unroll
            for (int nf = 0; nf < 2; ++nf) {
                const int slot = (s0 + nf + dr) & 7;
                const int baddr = RINGOFF + slot * SLOTB + lpx * 128
                                + ((cc ^ (lpx & 7)) << 4);
                bv[nf] = *(const bf16x8*)(LDS + baddr);
            }
#pragma unroll
            for (int mf = 0; mf < 2; ++mf)
#pragma unroll
                for (int nf = 0; nf < 2; ++nf)
                    acc[mf][nf] = __builtin_amdgcn_mfma_f32_16x16x32_bf16(
                        Areg[kl][k0][mf], bv[nf], acc[mf][nf], 0, 0, 0);
        }

        if (p < 15) WRITEPAIR(p + 2);      // vmcnt waits land here, then ds_write

        __syncthreads();                   // ring rotated; next pair visible

        // stores + acc reinit (overlap next phase's loads)
#pragma unroll
        for (int mf = 0; mf < 2; ++mf)
#pragma unroll
            for (int r = 0; r < 4; ++r) {
                const int o = oh * 32 + mf * 16 + lk * 4 + r;
#pragma unroll
                for (int nf = 0; nf < 2; ++nf) {
                    const int rowg = R0 + 2 * p + nf;
                    y[(((size_t)b * OO + o) * HH + rowg) * WW + ph * 64 + pxbase]
                        = acc[mf][nf][r];
                }
            }
#pragma unroll
        for (int mf = 0; mf < 2; ++mf)
#pragma unroll
            for (int nf = 0; nf < 2; ++nf)
#pragma unroll
                for (int r = 0; r < 4; ++r)
                    acc[mf][nf][r] = bbias[mf][r];

        s0 = (s0 + 2) & 7;
    }
}

extern "C" void kernel_launch(void* const* d_in, const int* in_sizes, int n_in,
                              void* d_out, int out_size, void* d_ws, size_t ws_size,
                              hipStream_t stream) {
    const float* addresses = (const float*)d_in[0];   // (B,O,I+1,F)
    const float* x         = (const float*)d_in[1];   // (B,I,H,W)
    const float* w_bank    = (const float*)d_in[2];   // (F,3,3)
    const float* b_bank    = (const float*)d_in[3];   // (F,)
    float* out = (float*)d_out;                       // (B,O,H,W)

    // ws layout: [bias 8KB][wT 2.25MB]
    float*  bias_ws = (float*)d_ws;
    __bf16* wT      = (__bf16*)((char*)d_ws + 8192);

    gen_weights<<<BB * OO, 64, 0, stream>>>(addresses, w_bank, b_bank, wT, bias_ws);
    conv_fused<<<256, 512, 0, stream>>>(x, wT, bias_ws, out);
}